// Round 17
// baseline (204.535 us; speedup 1.0000x reference)
//
#include <hip/hip_runtime.h>
#include <hip/hip_bf16.h>
#include <stdint.h>

typedef __attribute__((ext_vector_type(4))) int i32x4;
typedef __attribute__((ext_vector_type(4))) float f32x4;

#define THRESH 0.3f
#define Mdim 8192
#define Kdim 2048
#define Ndim 8192
#define NT 16   // K-tiles of 128 (i8)
#define NIT 8   // 2 K-tiles per iteration

// ---- Pass 1 (fused): blocks [0,8192) quantize x rows; blocks
// [8192, 8192+16384) ternarize+transpose w 32x32 tiles. x/w are read-once:
// NON-TEMPORAL loads (clang ext-vector f32x4 -- HIP float4 is rejected by
// the builtin) keep them from evicting xq/bt from L2/L3.
__global__ void prep_kernel(const float* __restrict__ x,
                            const float* __restrict__ w,
                            signed char* __restrict__ xq,
                            float* __restrict__ scales,
                            signed char* __restrict__ bt) {
  int bid = blockIdx.x;
  int tid = threadIdx.x;  // 256
  if (bid < Mdim) {
    // ---- xq part: q = rint(x * 127/rowmax); scales[row] = rowmax/127 ----
    int row = bid;
    const float* xr = x + (long)row * Kdim;
    f32x4 a = __builtin_nontemporal_load((const f32x4*)xr + tid * 2);
    f32x4 b = __builtin_nontemporal_load((const f32x4*)xr + tid * 2 + 1);
    float m = fmaxf(fmaxf(fmaxf(fabsf(a[0]), fabsf(a[1])),
                          fmaxf(fabsf(a[2]), fabsf(a[3]))),
                    fmaxf(fmaxf(fabsf(b[0]), fabsf(b[1])),
                          fmaxf(fabsf(b[2]), fabsf(b[3]))));
    #pragma unroll
    for (int d = 1; d < 64; d <<= 1) m = fmaxf(m, __shfl_xor(m, d, 64));
    __shared__ float red[4];
    if ((tid & 63) == 0) red[tid >> 6] = m;
    __syncthreads();
    m = fmaxf(fmaxf(red[0], red[1]), fmaxf(red[2], red[3]));
    m = fmaxf(m, 1e-20f);
    float inv = 127.0f / m;
    int q0 = (int)rintf(a[0] * inv), q1 = (int)rintf(a[1] * inv);
    int q2 = (int)rintf(a[2] * inv), q3 = (int)rintf(a[3] * inv);
    int q4 = (int)rintf(b[0] * inv), q5 = (int)rintf(b[1] * inv);
    int q6 = (int)rintf(b[2] * inv), q7 = (int)rintf(b[3] * inv);
    int lo = (q0 & 0xFF) | ((q1 & 0xFF) << 8) | ((q2 & 0xFF) << 16) |
             ((q3 & 0xFF) << 24);
    int hi = (q4 & 0xFF) | ((q5 & 0xFF) << 8) | ((q6 & 0xFF) << 16) |
             ((q7 & 0xFF) << 24);
    ((int2*)(xq + (long)row * Kdim))[tid] = make_int2(lo, hi);
    if (tid == 0) scales[row] = m / 127.0f;
  } else {
    // ---- tern_tr part: w [K][N] fp32 -> ternary i8 transposed [N][K] ----
    __shared__ signed char tile[32][33];
    int t0 = bid - Mdim;                    // 0 .. 256*64-1
    int n0 = (t0 & 255) * 32;               // 256 n-tiles
    int k0 = (t0 >> 8) * 32;                // 64 k-tiles
    int tx = tid & 31, ty = tid >> 5;       // (32, 8)
    #pragma unroll
    for (int j = 0; j < 4; ++j) {
      int k = k0 + ty + j * 8;
      float v = __builtin_nontemporal_load(&w[(long)k * Ndim + n0 + tx]);
      signed char tq = (fabsf(v) > THRESH) ? (v > 0.f ? 1 : -1) : 0;
      tile[ty + j * 8][tx] = tq;
    }
    __syncthreads();
    int nl = tid >> 3, kq = tid & 7;
    int b0 = tile[kq * 4 + 0][nl] & 0xFF;
    int b1 = tile[kq * 4 + 1][nl] & 0xFF;
    int b2 = tile[kq * 4 + 2][nl] & 0xFF;
    int b3 = tile[kq * 4 + 3][nl] & 0xFF;
    int pk = b0 | (b1 << 8) | (b2 << 16) | (b3 << 24);
    *(int*)(bt + (long)(n0 + nl) * Kdim + k0 + kq * 4) = pk;
  }
}

// ---- Pass 2: 256x256 i8 MFMA GEMM, C = scale_m * (Aq * Bt^T) ----
// R17 == R9 compute structure exactly (session best: 153us, MfmaUtil 45%,
// 0 conflicts). CHANGE: C stores are NON-TEMPORAL. R15's FETCH_SIZE = 98MB
// vs 32MB unique inputs (3x re-fetch): the 268MB C write-stream
// write-allocates in L2/L3 and evicts the A/B panels the XCD-chunk swizzle
// keeps hot, pushing mid-loop staging to ~900cy HBM latency. C is written
// once, never re-read -> nt store bypasses cache allocation.
__global__ void __launch_bounds__(512, 1) gemm8_kernel(
    const signed char* __restrict__ A,   // [8192][2048] i8 (M-major)
    const signed char* __restrict__ Bt,  // [8192][2048] i8 (N-major)
    const float* __restrict__ scales,    // [8192] per-M-row dequant scale
    float* __restrict__ C) {             // [8192][8192] fp32
  // layout: Abuf[j] at j*32768 (j=0..2); Bbuf[j] at 98304 + j*32768 (j=0..1)
  __shared__ __align__(128) char lds[163840];

  int bid = blockIdx.x;
  // 2D XCD-chunked swizzle (bijective over 32x32 tiles), R4-verified.
  int x = bid & 7;
  int o = bid >> 3;
  int c = o >> 5;
  int w = o & 31;
  int tm = x * 4 + (w >> 3);
  int tn = c * 8 + (w & 7);
  long arow0 = (long)tm * 256;
  long bcol0 = (long)tn * 256;

  int tid = threadIdx.x;
  int lane = tid & 63, wid = tid >> 6;
  int wr = wid >> 2, wc = wid & 3;  // 2M x 4N waves; per-wave C = 128x64
  int lr = lane & 15, lk = lane >> 4;

  // precomputed per-lane LDS read offsets (R7-verified algebra)
  int x7 = lr & 7;
  int voA[2], voB[2];
  #pragma unroll
  for (int ks = 0; ks < 2; ++ks) {
    int xo = ((ks * 4 + lk) ^ x7) << 4;
    voA[ks] = (wr * 128 + lr) * 128 + xo;
    voB[ks] = (wc * 64 + lr) * 128 + xo;
  }

  // precomputed per-thread staging offsets
  int go[2][2];  // [h][cc]
  #pragma unroll
  for (int h = 0; h < 2; ++h)
    #pragma unroll
    for (int cc = 0; cc < 2; ++cc) {
      int s = cc * 512 + tid;
      int r = h * 128 + (s >> 3);
      int co = (s & 7) ^ (r & 7);
      go[h][cc] = r * Kdim + co * 16;
    }
  const char* baseA = (const char*)A + arow0 * (long)Kdim;
  const char* baseB = (const char*)Bt + bcol0 * (long)Kdim;
  int ldst[2] = {(0 * 512 + wid * 64) * 16, (1 * 512 + wid * 64) * 16};

  auto stage = [&](int u, int which, int h) {
    if (u >= NT) return;
    const char* gb = which ? baseB : baseA;
    int base = (which ? (98304 + (u & 1) * 32768) : ((u % 3) * 32768)) +
               h * 16384;
    int ub = u * 128;
    #pragma unroll
    for (int cc = 0; cc < 2; ++cc) {
      const char* g = gb + (long)(go[h][cc] + ub);
      __builtin_amdgcn_global_load_lds(
          (const __attribute__((address_space(1))) void*)g,
          (__attribute__((address_space(3))) void*)(lds + base + ldst[cc]),
          16, 0, 0);
    }
  };

  i32x4 acc[8][4] = {};
  i32x4 bf[4][2];

  // prologue: tiles 0 and 1 fully staged (16 loads); wait for tile 0's 8.
  stage(0, 0, 0); stage(0, 0, 1); stage(0, 1, 0); stage(0, 1, 1);
  stage(1, 0, 0); stage(1, 0, 1); stage(1, 1, 0); stage(1, 1, 1);
  asm volatile("s_waitcnt vmcnt(8)" ::: "memory");
  __builtin_amdgcn_s_barrier();

  for (int it = 0; it < NIT; ++it) {
    int t = 2 * it;
    #pragma unroll
    for (int half = 0; half < 2; ++half) {
      int cur = t + half;
      const char* pA0 = lds + (cur % 3) * 32768 + voA[0];
      const char* pA1 = lds + (cur % 3) * 32768 + voA[1];
      const char* pB0 = lds + 98304 + (cur & 1) * 32768 + voB[0];
      const char* pB1 = lds + 98304 + (cur & 1) * 32768 + voB[1];
      int u = cur + 2;  // stage target tile
      #pragma unroll
      for (int q = 0; q < 4; ++q) {
        // ds-load A register subtile (immediates fold into ds_read offset)
        i32x4 af[2][2];
        #pragma unroll
        for (int m = 0; m < 2; ++m) {
          af[m][0] = *(const i32x4*)(pA0 + q * 4096 + m * 2048);
          af[m][1] = *(const i32x4*)(pA1 + q * 4096 + m * 2048);
        }
        if (q == 0) {
          #pragma unroll
          for (int n = 0; n < 4; ++n) {
            bf[n][0] = *(const i32x4*)(pB0 + n * 2048);
            bf[n][1] = *(const i32x4*)(pB1 + n * 2048);
          }
        }
        // stage one half-tile prefetch of tile cur+2
        if (q == 0) stage(u, 0, 0);
        else if (q == 1) stage(u, 0, 1);
        else if (q == 2) stage(u, 1, 0);
        else stage(u, 1, 1);

        if (q == 0) asm volatile("s_waitcnt lgkmcnt(8)" ::: "memory");
        __builtin_amdgcn_s_barrier();
        asm volatile("s_waitcnt lgkmcnt(0)" ::: "memory");
        __builtin_amdgcn_s_setprio(1);
        #pragma unroll
        for (int ks = 0; ks < 2; ++ks)
          #pragma unroll
          for (int m = 0; m < 2; ++m)
            #pragma unroll
            for (int n = 0; n < 4; ++n)
              acc[q * 2 + m][n] = __builtin_amdgcn_mfma_i32_16x16x64_i8(
                  af[m][ks], bf[n][ks], acc[q * 2 + m][n], 0, 0, 0);
        __builtin_amdgcn_s_setprio(0);
        if (q == 3) {
          // gate: exempt exactly this tile's 8 in-flight stages; drain
          // fully when they were skipped (round-2 tail lesson).
          if (u < NT) asm volatile("s_waitcnt vmcnt(8)" ::: "memory");
          else        asm volatile("s_waitcnt vmcnt(0)" ::: "memory");
        }
        __builtin_amdgcn_s_barrier();
      }
    }
  }

  // epilogue: D row = lk*4 + reg, col = lr; out = acc * scale[row].
  // NON-TEMPORAL stores: C is write-once, keep it out of L2/L3.
  #pragma unroll
  for (int m = 0; m < 8; ++m) {
    long row0 = arow0 + wr * 128 + m * 16 + lk * 4;
    f32x4 sc = *(const f32x4*)(scales + row0);
    #pragma unroll
    for (int n = 0; n < 4; ++n) {
      long col = bcol0 + wc * 64 + n * 16 + lr;
      #pragma unroll
      for (int r = 0; r < 4; ++r)
        __builtin_nontemporal_store((float)acc[m][n][r] * sc[r],
                                    &C[(row0 + r) * Ndim + col]);
    }
  }
}

// ---- fallback if d_ws is too small: simple tiled fp32 GEMM ----
__global__ void fallback_gemm(const float* __restrict__ x,
                              const float* __restrict__ w,
                              float* __restrict__ C) {
  __shared__ float As[16][17];
  __shared__ float Bs[16][17];
  int tx = threadIdx.x, ty = threadIdx.y;
  long row = (long)blockIdx.y * 16 + ty;
  long col = (long)blockIdx.x * 16 + tx;
  float s = 0.f;
  for (int k0 = 0; k0 < Kdim; k0 += 16) {
    As[ty][tx] = x[row * Kdim + k0 + tx];
    float v = w[(long)(k0 + ty) * Ndim + col];
    Bs[ty][tx] = (fabsf(v) > THRESH) ? (v > 0.f ? 1.f : -1.f) : 0.f;
    __syncthreads();
    #pragma unroll
    for (int k = 0; k < 16; ++k) s += As[ty][k] * Bs[k][tx];
    __syncthreads();
  }
  C[row * Ndim + col] = s;
}

extern "C" void kernel_launch(void* const* d_in, const int* in_sizes, int n_in,
                              void* d_out, int out_size, void* d_ws, size_t ws_size,
                              hipStream_t stream) {
  const float* x = (const float*)d_in[0];
  const float* w = (const float*)d_in[1];
  float* out = (float*)d_out;

  size_t abytes = (size_t)Mdim * Kdim;      // 16 MB i8
  size_t bbytes = (size_t)Ndim * Kdim;      // 16 MB i8
  size_t sbytes = (size_t)Mdim * 4;         // 32 KB scales

  if (ws_size >= abytes + bbytes + sbytes) {
    signed char* xq = (signed char*)d_ws;
    signed char* bt = (signed char*)d_ws + abytes;
    float* scales = (float*)((char*)d_ws + abytes + bbytes);
    prep_kernel<<<Mdim + (Ndim / 32) * (Kdim / 32), 256, 0, stream>>>(
        x, w, xq, scales, bt);
    gemm8_kernel<<<1024, 512, 0, stream>>>(xq, bt, scales, out);
  } else {
    fallback_gemm<<<dim3(Ndim / 16, Mdim / 16), dim3(16, 16), 0, stream>>>(x, w, out);
  }
}

// Round 18
// 183.411 us; speedup vs baseline: 1.1152x; 1.1152x over previous
//
#include <hip/hip_runtime.h>
#include <hip/hip_bf16.h>
#include <stdint.h>

typedef __attribute__((ext_vector_type(4))) int i32x4;
typedef __attribute__((ext_vector_type(4))) float f32x4;

#define THRESH 0.3f
#define Mdim 8192
#define Kdim 2048
#define Ndim 8192
#define NT 16   // K-tiles of 128 (i8)
#define NIT 8   // 2 K-tiles per iteration

// ---- Pass 1 (fused): blocks [0,8192) quantize x rows; blocks
// [8192, 8192+16384) ternarize+transpose w 32x32 tiles. (R15-verified.)
// NOTE R17 lesson: nt loads/stores net-negative here -- plain cached
// accesses let L2 write-combine the i8 outputs.
__global__ void prep_kernel(const float* __restrict__ x,
                            const float* __restrict__ w,
                            signed char* __restrict__ xq,
                            float* __restrict__ scales,
                            signed char* __restrict__ bt) {
  int bid = blockIdx.x;
  int tid = threadIdx.x;  // 256
  if (bid < Mdim) {
    // ---- xq part: q = rint(x * 127/rowmax); scales[row] = rowmax/127 ----
    int row = bid;
    const float* xr = x + (long)row * Kdim;
    float4 a = ((const float4*)xr)[tid * 2];
    float4 b = ((const float4*)xr)[tid * 2 + 1];
    float m = fmaxf(fmaxf(fmaxf(fabsf(a.x), fabsf(a.y)),
                          fmaxf(fabsf(a.z), fabsf(a.w))),
                    fmaxf(fmaxf(fabsf(b.x), fabsf(b.y)),
                          fmaxf(fabsf(b.z), fabsf(b.w))));
    #pragma unroll
    for (int d = 1; d < 64; d <<= 1) m = fmaxf(m, __shfl_xor(m, d, 64));
    __shared__ float red[4];
    if ((tid & 63) == 0) red[tid >> 6] = m;
    __syncthreads();
    m = fmaxf(fmaxf(red[0], red[1]), fmaxf(red[2], red[3]));
    m = fmaxf(m, 1e-20f);
    float inv = 127.0f / m;
    int q0 = (int)rintf(a.x * inv), q1 = (int)rintf(a.y * inv);
    int q2 = (int)rintf(a.z * inv), q3 = (int)rintf(a.w * inv);
    int q4 = (int)rintf(b.x * inv), q5 = (int)rintf(b.y * inv);
    int q6 = (int)rintf(b.z * inv), q7 = (int)rintf(b.w * inv);
    int lo = (q0 & 0xFF) | ((q1 & 0xFF) << 8) | ((q2 & 0xFF) << 16) |
             ((q3 & 0xFF) << 24);
    int hi = (q4 & 0xFF) | ((q5 & 0xFF) << 8) | ((q6 & 0xFF) << 16) |
             ((q7 & 0xFF) << 24);
    ((int2*)(xq + (long)row * Kdim))[tid] = make_int2(lo, hi);
    if (tid == 0) scales[row] = m / 127.0f;
  } else {
    // ---- tern_tr part: w [K][N] fp32 -> ternary i8 transposed [N][K] ----
    __shared__ signed char tile[32][33];
    int t0 = bid - Mdim;                    // 0 .. 256*64-1
    int n0 = (t0 & 255) * 32;               // 256 n-tiles
    int k0 = (t0 >> 8) * 32;                // 64 k-tiles
    int tx = tid & 31, ty = tid >> 5;       // (32, 8)
    #pragma unroll
    for (int j = 0; j < 4; ++j) {
      int k = k0 + ty + j * 8;
      float v = w[(long)k * Ndim + n0 + tx];
      signed char tq = (fabsf(v) > THRESH) ? (v > 0.f ? 1 : -1) : 0;
      tile[ty + j * 8][tx] = tq;
    }
    __syncthreads();
    int nl = tid >> 3, kq = tid & 7;
    int b0 = tile[kq * 4 + 0][nl] & 0xFF;
    int b1 = tile[kq * 4 + 1][nl] & 0xFF;
    int b2 = tile[kq * 4 + 2][nl] & 0xFF;
    int b3 = tile[kq * 4 + 3][nl] & 0xFF;
    int pk = b0 | (b1 << 8) | (b2 << 16) | (b3 << 24);
    *(int*)(bt + (long)(n0 + nl) * Kdim + k0 + kq * 4) = pk;
  }
}

// ---- Pass 2: 256x256 i8 MFMA GEMM, C = scale_m * (Aq * Bt^T) ----
// R18 == R15/R9 exactly (session best: gemm ~154us, MfmaUtil 45%,
// 0 bank conflicts, absmax 0.90625). Final configuration after 12
// structural probes:
//   schedule variants (R5-R8,R10,R13): null/negative
//   B-direct-from-global (R11): -100us (uncoalesced)
//   2 blocks/CU occupancy (R12): null
//   32x32x32 shape (R14): null (ops-rate cap, not per-inst cost)
//   nt C-stores (R17): -30us (defeats L2 write-combining)
// Measured family ceiling: ~45% of i8 MFMA ubench (729-745 ops/cy/SIMD
// invariant across shapes/structures/occupancies) with LDS+staging
// traffic present. HBM 366MB ~= 58us << 155us wall: not BW-bound.
__global__ void __launch_bounds__(512, 1) gemm8_kernel(
    const signed char* __restrict__ A,   // [8192][2048] i8 (M-major)
    const signed char* __restrict__ Bt,  // [8192][2048] i8 (N-major)
    const float* __restrict__ scales,    // [8192] per-M-row dequant scale
    float* __restrict__ C) {             // [8192][8192] fp32
  // layout: Abuf[j] at j*32768 (j=0..2); Bbuf[j] at 98304 + j*32768 (j=0..1)
  __shared__ __align__(128) char lds[163840];

  int bid = blockIdx.x;
  // 2D XCD-chunked swizzle (bijective over 32x32 tiles), R4-verified.
  int x = bid & 7;
  int o = bid >> 3;
  int c = o >> 5;
  int w = o & 31;
  int tm = x * 4 + (w >> 3);
  int tn = c * 8 + (w & 7);
  long arow0 = (long)tm * 256;
  long bcol0 = (long)tn * 256;

  int tid = threadIdx.x;
  int lane = tid & 63, wid = tid >> 6;
  int wr = wid >> 2, wc = wid & 3;  // 2M x 4N waves; per-wave C = 128x64
  int lr = lane & 15, lk = lane >> 4;

  // precomputed per-lane LDS read offsets (R7-verified algebra)
  int x7 = lr & 7;
  int voA[2], voB[2];
  #pragma unroll
  for (int ks = 0; ks < 2; ++ks) {
    int xo = ((ks * 4 + lk) ^ x7) << 4;
    voA[ks] = (wr * 128 + lr) * 128 + xo;
    voB[ks] = (wc * 64 + lr) * 128 + xo;
  }

  // precomputed per-thread staging offsets
  int go[2][2];  // [h][cc]
  #pragma unroll
  for (int h = 0; h < 2; ++h)
    #pragma unroll
    for (int cc = 0; cc < 2; ++cc) {
      int s = cc * 512 + tid;
      int r = h * 128 + (s >> 3);
      int co = (s & 7) ^ (r & 7);
      go[h][cc] = r * Kdim + co * 16;
    }
  const char* baseA = (const char*)A + arow0 * (long)Kdim;
  const char* baseB = (const char*)Bt + bcol0 * (long)Kdim;
  int ldst[2] = {(0 * 512 + wid * 64) * 16, (1 * 512 + wid * 64) * 16};

  auto stage = [&](int u, int which, int h) {
    if (u >= NT) return;
    const char* gb = which ? baseB : baseA;
    int base = (which ? (98304 + (u & 1) * 32768) : ((u % 3) * 32768)) +
               h * 16384;
    int ub = u * 128;
    #pragma unroll
    for (int cc = 0; cc < 2; ++cc) {
      const char* g = gb + (long)(go[h][cc] + ub);
      __builtin_amdgcn_global_load_lds(
          (const __attribute__((address_space(1))) void*)g,
          (__attribute__((address_space(3))) void*)(lds + base + ldst[cc]),
          16, 0, 0);
    }
  };

  i32x4 acc[8][4] = {};
  i32x4 bf[4][2];

  // prologue: tiles 0 and 1 fully staged (16 loads); wait for tile 0's 8.
  stage(0, 0, 0); stage(0, 0, 1); stage(0, 1, 0); stage(0, 1, 1);
  stage(1, 0, 0); stage(1, 0, 1); stage(1, 1, 0); stage(1, 1, 1);
  asm volatile("s_waitcnt vmcnt(8)" ::: "memory");
  __builtin_amdgcn_s_barrier();

  for (int it = 0; it < NIT; ++it) {
    int t = 2 * it;
    #pragma unroll
    for (int half = 0; half < 2; ++half) {
      int cur = t + half;
      const char* pA0 = lds + (cur % 3) * 32768 + voA[0];
      const char* pA1 = lds + (cur % 3) * 32768 + voA[1];
      const char* pB0 = lds + 98304 + (cur & 1) * 32768 + voB[0];
      const char* pB1 = lds + 98304 + (cur & 1) * 32768 + voB[1];
      int u = cur + 2;  // stage target tile
      #pragma unroll
      for (int q = 0; q < 4; ++q) {
        // ds-load A register subtile (immediates fold into ds_read offset)
        i32x4 af[2][2];
        #pragma unroll
        for (int m = 0; m < 2; ++m) {
          af[m][0] = *(const i32x4*)(pA0 + q * 4096 + m * 2048);
          af[m][1] = *(const i32x4*)(pA1 + q * 4096 + m * 2048);
        }
        if (q == 0) {
          #pragma unroll
          for (int n = 0; n < 4; ++n) {
            bf[n][0] = *(const i32x4*)(pB0 + n * 2048);
            bf[n][1] = *(const i32x4*)(pB1 + n * 2048);
          }
        }
        // stage one half-tile prefetch of tile cur+2
        if (q == 0) stage(u, 0, 0);
        else if (q == 1) stage(u, 0, 1);
        else if (q == 2) stage(u, 1, 0);
        else stage(u, 1, 1);

        if (q == 0) asm volatile("s_waitcnt lgkmcnt(8)" ::: "memory");
        __builtin_amdgcn_s_barrier();
        asm volatile("s_waitcnt lgkmcnt(0)" ::: "memory");
        __builtin_amdgcn_s_setprio(1);
        #pragma unroll
        for (int ks = 0; ks < 2; ++ks)
          #pragma unroll
          for (int m = 0; m < 2; ++m)
            #pragma unroll
            for (int n = 0; n < 4; ++n)
              acc[q * 2 + m][n] = __builtin_amdgcn_mfma_i32_16x16x64_i8(
                  af[m][ks], bf[n][ks], acc[q * 2 + m][n], 0, 0, 0);
        __builtin_amdgcn_s_setprio(0);
        if (q == 3) {
          // gate: exempt exactly this tile's 8 in-flight stages; drain
          // fully when they were skipped (round-2 tail lesson).
          if (u < NT) asm volatile("s_waitcnt vmcnt(8)" ::: "memory");
          else        asm volatile("s_waitcnt vmcnt(0)" ::: "memory");
        }
        __builtin_amdgcn_s_barrier();
      }
    }
  }

  // epilogue: D row = lk*4 + reg, col = lr; out = acc * scale[row]
  #pragma unroll
  for (int m = 0; m < 8; ++m) {
    long row0 = arow0 + wr * 128 + m * 16 + lk * 4;
    f32x4 sc = *(const f32x4*)(scales + row0);
    #pragma unroll
    for (int n = 0; n < 4; ++n) {
      long col = bcol0 + wc * 64 + n * 16 + lr;
      #pragma unroll
      for (int r = 0; r < 4; ++r)
        C[(row0 + r) * Ndim + col] = (float)acc[m][n][r] * sc[r];
    }
  }
}

// ---- fallback if d_ws is too small: simple tiled fp32 GEMM ----
__global__ void fallback_gemm(const float* __restrict__ x,
                              const float* __restrict__ w,
                              float* __restrict__ C) {
  __shared__ float As[16][17];
  __shared__ float Bs[16][17];
  int tx = threadIdx.x, ty = threadIdx.y;
  long row = (long)blockIdx.y * 16 + ty;
  long col = (long)blockIdx.x * 16 + tx;
  float s = 0.f;
  for (int k0 = 0; k0 < Kdim; k0 += 16) {
    As[ty][tx] = x[row * Kdim + k0 + tx];
    float v = w[(long)(k0 + ty) * Ndim + col];
    Bs[ty][tx] = (fabsf(v) > THRESH) ? (v > 0.f ? 1.f : -1.f) : 0.f;
    __syncthreads();
    #pragma unroll
    for (int k = 0; k < 16; ++k) s += As[ty][k] * Bs[k][tx];
    __syncthreads();
  }
  C[row * Ndim + col] = s;
}

extern "C" void kernel_launch(void* const* d_in, const int* in_sizes, int n_in,
                              void* d_out, int out_size, void* d_ws, size_t ws_size,
                              hipStream_t stream) {
  const float* x = (const float*)d_in[0];
  const float* w = (const float*)d_in[1];
  float* out = (float*)d_out;

  size_t abytes = (size_t)Mdim * Kdim;      // 16 MB i8
  size_t bbytes = (size_t)Ndim * Kdim;      // 16 MB i8
  size_t sbytes = (size_t)Mdim * 4;         // 32 KB scales

  if (ws_size >= abytes + bbytes + sbytes) {
    signed char* xq = (signed char*)d_ws;
    signed char* bt = (signed char*)d_ws + abytes;
    float* scales = (float*)((char*)d_ws + abytes + bbytes);
    prep_kernel<<<Mdim + (Ndim / 32) * (Kdim / 32), 256, 0, stream>>>(
        x, w, xq, scales, bt);
    gemm8_kernel<<<1024, 512, 0, stream>>>(xq, bt, scales, out);
  } else {
    fallback_gemm<<<dim3(Ndim / 16, Mdim / 16), dim3(16, 16), 0, stream>>>(x, w, out);
  }
}